// Round 8
// baseline (167.548 us; speedup 1.0000x reference)
//
#include <hip/hip_runtime.h>

#define EPS 1e-8f

typedef float f4 __attribute__((ext_vector_type(4)));

namespace {
constexpr int Bc = 128;
constexpr int Tc = 128;
constexpr int Dc = 512;
constexpr int D4 = Dc / 4;                        // 128 float4 per row
constexpr int COLS_PER_TENSOR = Bc * D4;          // 16384 (b,d4) columns
constexpr int THREADS1 = 64;                      // one wave per block
constexpr int GRID1 = 9 * COLS_PER_TENSOR / THREADS1;  // 2304 = 9 blocks/CU exactly
constexpr int PRODUCERS_PER_B = 18;               // 9 tensors * 2 half-d blocks
constexpr size_t FMEAN_ELEMS = (size_t)9 * Bc * Dc;    // 589824 floats
}

// Fused: phase 1 = per-column T-sums (R6 winner structure). Each block covers
// 64 columns = one (q, b, d-half) slice. After its stores, device-release +
// atomicAdd(cnt[b]); the 18th arriver acquires and finishes batch element b
// entirely in-wave. No grid barrier; finishers overlap remaining phase 1.
__global__ __launch_bounds__(64, 2) void hm_fused_kernel(
    const float* __restrict__ f0, const float* __restrict__ f1,
    const float* __restrict__ f2, const float* __restrict__ f3,
    const float* __restrict__ f4_, const float* __restrict__ f5,
    const float* __restrict__ f6, const float* __restrict__ f7,
    const float* __restrict__ f8, const float* __restrict__ joint,
    float* __restrict__ fmean, unsigned int* __restrict__ cnt,
    float* __restrict__ out)
{
    // ---------------- phase 1: T-sum for this block's 64 columns ----------------
    const float* fs[9] = {f0, f1, f2, f3, f4_, f5, f6, f7, f8};
    const int gid = blockIdx.x * THREADS1 + threadIdx.x;   // 0 .. 147455
    const int q   = gid >> 14;                             // / 16384
    const int idx = gid & (COLS_PER_TENSOR - 1);           // b*D4 + d4
    const int b   = idx >> 7;                              // / D4  (uniform per block)
    const int d4  = idx & (D4 - 1);

    const f4* src = reinterpret_cast<const f4*>(fs[q])
                  + (size_t)b * Tc * D4 + d4;

    f4 acc[4];
    #pragma unroll
    for (int u = 0; u < 4; ++u) acc[u] = (f4){0.f, 0.f, 0.f, 0.f};

    for (int t0 = 0; t0 < Tc; t0 += 16) {
        f4 buf[16];
        #pragma unroll
        for (int u = 0; u < 16; ++u)
            buf[u] = src[(size_t)(t0 + u) * D4];
        #pragma unroll
        for (int u = 0; u < 16; ++u)
            acc[u & 3] += buf[u];
    }

    f4 r = (acc[0] + acc[1]) + (acc[2] + acc[3]);
    reinterpret_cast<f4*>(fmean)[(size_t)q * COLS_PER_TENSOR + idx] = r;

    // ---------------- decoupled completion: last of 18 producers for b -------
    __threadfence();                       // release: flush wave's stores device-wide
    int old = 0;
    if (threadIdx.x == 0)
        old = (int)atomicAdd(&cnt[b], 1u); // device-scope by default
    old = __shfl(old, 0, 64);
    if (old != PRODUCERS_PER_B - 1) return;
    __threadfence();                       // acquire: see all producers' fmean writes

    // ---------------- phase 2: finish batch element b, one wave --------------
    const int t = threadIdx.x;             // 0..63
    const float invT = 1.0f / (float)Tc;

    // pass A: num[q] = dot(joint[b,:], fmean[q,b,:]) (fmean holds T-sums)
    float jd[8];
    float pnum[9];
    #pragma unroll
    for (int q2 = 0; q2 < 9; ++q2) pnum[q2] = 0.f;
    #pragma unroll
    for (int k = 0; k < 8; ++k) {
        const int d = k * 64 + t;
        jd[k] = joint[(size_t)b * Dc + d];
        #pragma unroll
        for (int q2 = 0; q2 < 9; ++q2)
            pnum[q2] += jd[k] * fmean[((size_t)q2 * Bc + b) * Dc + d];
    }
    #pragma unroll
    for (int q2 = 0; q2 < 9; ++q2)
        #pragma unroll
        for (int off = 32; off > 0; off >>= 1)
            pnum[q2] += __shfl_xor(pnum[q2], off, 64);

    float bw[3][3];
    #pragma unroll
    for (int i = 0; i < 3; ++i) {
        const float n0 = pnum[i * 3] * invT, n1 = pnum[i * 3 + 1] * invT,
                    n2 = pnum[i * 3 + 2] * invT;
        const float rdenom = 1.0f / (n0 + n1 + n2 + EPS);
        bw[i][0] = n0 * rdenom; bw[i][1] = n1 * rdenom; bw[i][2] = n2 * rdenom;
    }

    // pass B: fii = sum_j bw*fm; num2[i] = dot(joint, fii)
    float fii[8][3];
    float pnum2[3] = {0.f, 0.f, 0.f};
    #pragma unroll
    for (int k = 0; k < 8; ++k) {
        const int d = k * 64 + t;
        float fm[9];
        #pragma unroll
        for (int q2 = 0; q2 < 9; ++q2)
            fm[q2] = fmean[((size_t)q2 * Bc + b) * Dc + d] * invT;
        #pragma unroll
        for (int i = 0; i < 3; ++i) {
            fii[k][i] = bw[i][0] * fm[i * 3 + 0]
                      + bw[i][1] * fm[i * 3 + 1]
                      + bw[i][2] * fm[i * 3 + 2];
            pnum2[i] += jd[k] * fii[k][i];
        }
    }
    #pragma unroll
    for (int i = 0; i < 3; ++i)
        #pragma unroll
        for (int off = 32; off > 0; off >>= 1)
            pnum2[i] += __shfl_xor(pnum2[i], off, 64);

    const float rd2 = 1.0f / (pnum2[0] + pnum2[1] + pnum2[2] + EPS);
    const float lam0 = pnum2[0] * rd2, lam1 = pnum2[1] * rd2, lam2 = pnum2[2] * rd2;

    #pragma unroll
    for (int k = 0; k < 8; ++k) {
        const int d = k * 64 + t;
        out[(size_t)b * Dc + d] =
            lam0 * fii[k][0] + lam1 * fii[k][1] + lam2 * fii[k][2];
    }
}

extern "C" void kernel_launch(void* const* d_in, const int* in_sizes, int n_in,
                              void* d_out, int out_size, void* d_ws, size_t ws_size,
                              hipStream_t stream) {
    const float* joint = (const float*)d_in[0];
    const float* f[9];
    for (int q = 0; q < 9; ++q) f[q] = (const float*)d_in[1 + q];
    float* out   = (float*)d_out;
    float* fmean = (float*)d_ws;                       // 1.18 MB of T-sums
    unsigned int* cnt = (unsigned int*)((char*)d_ws + FMEAN_ELEMS * sizeof(float));

    // Counters must be zero every call (ws is poisoned 0xAA once, never restored).
    hipMemsetAsync(cnt, 0, Bc * sizeof(unsigned int), stream);

    hipLaunchKernelGGL(hm_fused_kernel, dim3(GRID1), dim3(THREADS1), 0, stream,
                       f[0], f[1], f[2], f[3], f[4], f[5], f[6], f[7], f[8],
                       joint, fmean, cnt, out);
}

// Round 9
// 53.354 us; speedup vs baseline: 3.1403x; 3.1403x over previous
//
#include <hip/hip_runtime.h>

#define EPS 1e-8f

typedef float f4 __attribute__((ext_vector_type(4)));

namespace {
constexpr int Bc = 128;
constexpr int Tc = 128;
constexpr int Dc = 512;
constexpr int D4 = Dc / 4;                        // 128 float4 per row
constexpr int COLS_PER_TENSOR = Bc * D4;          // 16384 (b,d4) columns
constexpr int THREADS1 = 64;                      // one wave per block
constexpr int GRID1 = 9 * COLS_PER_TENSOR / THREADS1;  // 2304 = 9 blocks/CU exactly
}

// Kernel 1: fmean[q][b][d] = sum_t f_q[b][t][d]  (divide by T happens in kernel 2)
// One thread per (q,b,d4) column; 16-deep explicit load staging for MLP.
// R6 winner: 53.7 us. Fusion attempts (coop grid.sync R7, fence+atomic R8)
// both lose: coop launch fails at 2304 blocks; device fences force per-XCD L2
// writebacks that collapse the cache path (219 us).
__global__ __launch_bounds__(64, 2) void hm_mean_kernel(
    const float* __restrict__ f0, const float* __restrict__ f1,
    const float* __restrict__ f2, const float* __restrict__ f3,
    const float* __restrict__ f4_, const float* __restrict__ f5,
    const float* __restrict__ f6, const float* __restrict__ f7,
    const float* __restrict__ f8, float* __restrict__ fmean)
{
    const float* fs[9] = {f0, f1, f2, f3, f4_, f5, f6, f7, f8};
    const int gid = blockIdx.x * THREADS1 + threadIdx.x;   // 0 .. 147455
    const int q   = gid >> 14;                             // / 16384
    const int idx = gid & (COLS_PER_TENSOR - 1);           // b*D4 + d4
    const int b   = idx >> 7;                              // / D4
    const int d4  = idx & (D4 - 1);

    const f4* src = reinterpret_cast<const f4*>(fs[q])
                  + (size_t)b * Tc * D4 + d4;

    f4 acc[4];
    #pragma unroll
    for (int u = 0; u < 4; ++u) acc[u] = (f4){0.f, 0.f, 0.f, 0.f};

    for (int t0 = 0; t0 < Tc; t0 += 16) {
        f4 buf[16];
        #pragma unroll
        for (int u = 0; u < 16; ++u)
            buf[u] = src[(size_t)(t0 + u) * D4];
        #pragma unroll
        for (int u = 0; u < 16; ++u)
            acc[u & 3] += buf[u];
    }

    f4 r = (acc[0] + acc[1]) + (acc[2] + acc[3]);
    reinterpret_cast<f4*>(fmean)[(size_t)q * COLS_PER_TENSOR + idx] = r;
}

// Kernel 2: all the small linear algebra. One block (256 thr) per batch element b.
__global__ __launch_bounds__(256) void hm_final_kernel(
    const float* __restrict__ joint, const float* __restrict__ fmean,
    float* __restrict__ out)
{
    const int b    = blockIdx.x;
    const int tid  = threadIdx.x;
    const int lane = tid & 63;
    const int wave = tid >> 6;

    __shared__ float sm_red[4][9];
    __shared__ float sm_red2[4][3];
    __shared__ float sm_num[9];
    __shared__ float sm_num2[3];

    const float invT = 1.0f / (float)Tc;

    float jd[2];
    float fm[2][9];
    float pnum[9];
    #pragma unroll
    for (int q = 0; q < 9; ++q) pnum[q] = 0.f;

    #pragma unroll
    for (int r = 0; r < 2; ++r) {
        const int d = tid + r * 256;
        jd[r] = joint[(size_t)b * Dc + d];
        #pragma unroll
        for (int q = 0; q < 9; ++q) {
            fm[r][q] = fmean[((size_t)q * Bc + b) * Dc + d] * invT;
            pnum[q] += jd[r] * fm[r][q];
        }
    }

    #pragma unroll
    for (int q = 0; q < 9; ++q)
        #pragma unroll
        for (int off = 32; off > 0; off >>= 1)
            pnum[q] += __shfl_down(pnum[q], off, 64);
    if (lane == 0)
        #pragma unroll
        for (int q = 0; q < 9; ++q) sm_red[wave][q] = pnum[q];
    __syncthreads();
    if (tid < 9)
        sm_num[tid] = sm_red[0][tid] + sm_red[1][tid] + sm_red[2][tid] + sm_red[3][tid];
    __syncthreads();

    float num[9];
    #pragma unroll
    for (int q = 0; q < 9; ++q) num[q] = sm_num[q];
    float bw[3][3];
    #pragma unroll
    for (int i = 0; i < 3; ++i) {
        const float denom = num[i * 3] + num[i * 3 + 1] + num[i * 3 + 2] + EPS;
        const float rdenom = 1.0f / denom;
        #pragma unroll
        for (int j = 0; j < 3; ++j) bw[i][j] = num[i * 3 + j] * rdenom;
    }

    float fii[2][3];
    float pnum2[3] = {0.f, 0.f, 0.f};
    #pragma unroll
    for (int r = 0; r < 2; ++r)
        #pragma unroll
        for (int i = 0; i < 3; ++i) {
            fii[r][i] = bw[i][0] * fm[r][i * 3 + 0]
                      + bw[i][1] * fm[r][i * 3 + 1]
                      + bw[i][2] * fm[r][i * 3 + 2];
            pnum2[i] += jd[r] * fii[r][i];
        }

    #pragma unroll
    for (int i = 0; i < 3; ++i)
        #pragma unroll
        for (int off = 32; off > 0; off >>= 1)
            pnum2[i] += __shfl_down(pnum2[i], off, 64);
    if (lane == 0)
        #pragma unroll
        for (int i = 0; i < 3; ++i) sm_red2[wave][i] = pnum2[i];
    __syncthreads();
    if (tid < 3)
        sm_num2[tid] = sm_red2[0][tid] + sm_red2[1][tid] + sm_red2[2][tid] + sm_red2[3][tid];
    __syncthreads();

    const float denom2 = sm_num2[0] + sm_num2[1] + sm_num2[2] + EPS;
    const float rd2 = 1.0f / denom2;
    float lam[3];
    #pragma unroll
    for (int i = 0; i < 3; ++i) lam[i] = sm_num2[i] * rd2;

    #pragma unroll
    for (int r = 0; r < 2; ++r) {
        const int d = tid + r * 256;
        out[(size_t)b * Dc + d] =
            lam[0] * fii[r][0] + lam[1] * fii[r][1] + lam[2] * fii[r][2];
    }
}

extern "C" void kernel_launch(void* const* d_in, const int* in_sizes, int n_in,
                              void* d_out, int out_size, void* d_ws, size_t ws_size,
                              hipStream_t stream) {
    const float* joint = (const float*)d_in[0];
    const float* f[9];
    for (int q = 0; q < 9; ++q) f[q] = (const float*)d_in[1 + q];
    float* out = (float*)d_out;
    float* fmean = (float*)d_ws;  // 9*B*D floats = 1.18 MB (T-sums, not yet /T)

    hipLaunchKernelGGL(hm_mean_kernel, dim3(GRID1), dim3(THREADS1), 0, stream,
                       f[0], f[1], f[2], f[3], f[4], f[5], f[6], f[7], f[8], fmean);
    hipLaunchKernelGGL(hm_final_kernel, dim3(Bc), dim3(256), 0, stream,
                       joint, fmean, out);
}